// Round 7
// baseline (193.472 us; speedup 1.0000x reference)
//
#include <hip/hip_runtime.h>
#include <math.h>

#define SDR_DIM 65536
#define HIDDEN  4096
#define NMOD    2048
#define PHASE   4096
#define NGRP    (SDR_DIM / 16)    // 4096 groups of 16 floats (64B lines)
#define NORM_EPS 1e-8f

typedef float fx4 __attribute__((ext_vector_type(4)));

__device__ __forceinline__ float waveReduce(float v) {
  #pragma unroll
  for (int off = 32; off > 0; off >>= 1) v += __shfl_down(v, off);
  return v;
}

__device__ __forceinline__ fx4 ntload4(const fx4* p) {
  return __builtin_nontemporal_load(p);
}

// ---------------------------------------------------------------------------
// Kernel 1a: per-group 16-bit activity masks (16 blocks) + zero accums.
// ---------------------------------------------------------------------------
__global__ __launch_bounds__(256) void k_masks(const float* __restrict__ sdr,
                                               unsigned int* __restrict__ masks,
                                               float* __restrict__ accums) {
  int g = blockIdx.x * 256 + threadIdx.x;   // 0..NGRP-1
  if (blockIdx.x == 0 && threadIdx.x < 2) accums[threadIdx.x] = 0.0f;
  const fx4* s4 = (const fx4*)sdr;
  unsigned int m = 0;
  #pragma unroll
  for (int q = 0; q < 4; ++q) {
    fx4 v = s4[g * 4 + q];
    m |= (v.x > 0.0f ? 1u : 0u) << (q * 4 + 0);
    m |= (v.y > 0.0f ? 1u : 0u) << (q * 4 + 1);
    m |= (v.z > 0.0f ? 1u : 0u) << (q * 4 + 2);
    m |= (v.w > 0.0f ? 1u : 0u) << (q * 4 + 3);
  }
  masks[g] = m;
}

// ---------------------------------------------------------------------------
// Kernel 1b: single-block scan (L2-hot masks) -> packed list (ascending g).
// Also: ntc flag = any(h_tc != 0).
// ---------------------------------------------------------------------------
__global__ __launch_bounds__(1024) void k_emit(const unsigned int* __restrict__ masks,
                                               const float* __restrict__ htc,
                                               unsigned int* __restrict__ packed,
                                               int* __restrict__ ngrp,
                                               int* __restrict__ ntc) {
  __shared__ int wsum[16];
  __shared__ int sflag;
  int t = threadIdx.x;
  int lane = t & 63, wave = t >> 6;
  if (t == 0) sflag = 0;
  __syncthreads();

  bool nz = false;
  #pragma unroll
  for (int i = 0; i < PHASE / 1024; ++i) nz |= (htc[t + i * 1024] != 0.0f);
  if (nz) sflag = 1;

  unsigned int m[4];
  int cnt = 0;
  #pragma unroll
  for (int g = 0; g < 4; ++g) {
    m[g] = masks[t * 4 + g];
    cnt += (m[g] != 0u) ? 1 : 0;
  }
  int inc = cnt;
  #pragma unroll
  for (int d = 1; d < 64; d <<= 1) {
    int v = __shfl_up(inc, d);
    if (lane >= d) inc += v;
  }
  if (lane == 63) wsum[wave] = inc;
  __syncthreads();
  if (t == 0) {
    int s = 0;
    #pragma unroll
    for (int w = 0; w < 16; ++w) { int v = wsum[w]; wsum[w] = s; s += v; }
    *ngrp = s;
    *ntc = sflag;
  }
  __syncthreads();
  int off = wsum[wave] + (inc - cnt);
  #pragma unroll
  for (int g = 0; g < 4; ++g) {
    if (m[g]) packed[off++] = (m[g] << 16) | (unsigned int)(t * 4 + g);
  }
}

// ---------------------------------------------------------------------------
// Kernel 2: h = relu(W1 @ sdr + b1), sparse 64B-line streaming.
// 1 row/wave, 4 waves/block; lane cluster of 4 per 64B line; 8 lines in
// flight per lane (R4-proven depth — 16-deep regressed via VGPR pressure).
// At the 128B-granularity HBM roofline: ~865MB at ~6.2 TB/s.
// ---------------------------------------------------------------------------
__global__ __launch_bounds__(256) void k_h(const float* __restrict__ W1,
                                           const float* __restrict__ b1,
                                           const unsigned int* __restrict__ packed,
                                           const int* __restrict__ ngrpp,
                                           float* __restrict__ h) {
  int lane = threadIdx.x & 63;
  int row = blockIdx.x * 4 + (threadIdx.x >> 6);
  int n = *ngrpp;
  int sub = lane & 3, slot = lane >> 2;
  int shift = 16 + sub * 4;
  const fx4* __restrict__ Wr4 = (const fx4*)(W1 + (size_t)row * SDR_DIM);

  float acc = 0.0f;
  int k = slot;
  for (; k + 112 < n; k += 128) {
    unsigned int e[8];
    fx4 f[8];
    #pragma unroll
    for (int j = 0; j < 8; ++j) e[j] = packed[k + 16 * j];
    #pragma unroll
    for (int j = 0; j < 8; ++j) f[j] = ntload4(Wr4 + ((e[j] & 0xFFFFu) * 4 + sub));
    #pragma unroll
    for (int j = 0; j < 8; ++j) {
      unsigned int mj = (e[j] >> shift) & 0xFu;
      acc += (mj & 1u) ? f[j].x : 0.0f;
      acc += (mj & 2u) ? f[j].y : 0.0f;
      acc += (mj & 4u) ? f[j].z : 0.0f;
      acc += (mj & 8u) ? f[j].w : 0.0f;
    }
  }
  for (; k < n; k += 16) {
    unsigned int e = packed[k];
    fx4 f = ntload4(Wr4 + ((e & 0xFFFFu) * 4 + sub));
    unsigned int mj = (e >> shift) & 0xFu;
    acc += (mj & 1u) ? f.x : 0.0f;
    acc += (mj & 2u) ? f.y : 0.0f;
    acc += (mj & 4u) ? f.z : 0.0f;
    acc += (mj & 8u) ? f.w : 0.0f;
  }

  acc = waveReduce(acc);
  if (lane == 0) {
    float v = acc + b1[row];
    h[row] = v > 0.0f ? v : 0.0f;
  }
}

// ---------------------------------------------------------------------------
// Kernel 3: z_ego = W2 @ h + b2 (1 row/wave) + rotation + ||z_ego||^2 atomic.
// ---------------------------------------------------------------------------
__global__ __launch_bounds__(256) void k_z_rot(const float* __restrict__ W,
                                               const float* __restrict__ x,
                                               const float* __restrict__ b,
                                               const float* __restrict__ velW,
                                               const float* __restrict__ vel,
                                               float* __restrict__ zflat,
                                               float* __restrict__ accums) {
  __shared__ float zs[4];
  int lane = threadIdx.x & 63;
  int wave = threadIdx.x >> 6;
  int row = blockIdx.x * 4 + wave;
  const fx4* __restrict__ Wr = (const fx4*)(W + (size_t)row * HIDDEN);
  const fx4* __restrict__ xv = (const fx4*)x;
  float acc = 0.0f;
  #pragma unroll 4
  for (int k = lane; k < HIDDEN / 4; k += 64) {
    fx4 w = ntload4(Wr + k); fx4 v = xv[k];
    acc += w.x * v.x + w.y * v.y + w.z * v.z + w.w * v.w;
  }
  acc = waveReduce(acc);
  if (lane == 0) zs[wave] = acc + b[row];
  __syncthreads();
  if (threadIdx.x < 2) {
    int m = blockIdx.x * 2 + threadIdx.x;      // pair index
    float xx = zs[2 * threadIdx.x];
    float yy = zs[2 * threadIdx.x + 1];
    float th = velW[2 * m] * vel[0] + velW[2 * m + 1] * vel[1];
    float s, c;
    sincosf(th, &s, &c);
    zflat[2 * m]     = c * xx - s * yy;
    zflat[2 * m + 1] = s * xx + c * yy;
    float n2 = xx * xx + yy * yy;
    n2 += __shfl_down(n2, 1);
    if (threadIdx.x == 0) atomicAdd(accums + 0, n2);
  }
}

// ---------------------------------------------------------------------------
// Kernel 4: h_new = tanh(W_tc@z_flat + [W_ht@h_tc if ntc]); zfb write +
// ||z_fb||^2 atomic. 1 row/wave.
// ---------------------------------------------------------------------------
__global__ __launch_bounds__(256) void k_hnew(const float* __restrict__ Wtc,
                                              const float* __restrict__ Wht,
                                              const float* __restrict__ zflat,
                                              const float* __restrict__ htc,
                                              const float* __restrict__ gnrt,
                                              const int* __restrict__ ntc,
                                              float* __restrict__ zfb,
                                              float* __restrict__ accums) {
  __shared__ float red[4];
  int lane = threadIdx.x & 63;
  int wave = threadIdx.x >> 6;
  int row = blockIdx.x * 4 + wave;
  const fx4* __restrict__ Ar = (const fx4*)(Wtc + (size_t)row * PHASE);
  const fx4* __restrict__ xv = (const fx4*)zflat;
  float acc = 0.0f;
  #pragma unroll 4
  for (int k = lane; k < PHASE / 4; k += 64) {
    fx4 a = ntload4(Ar + k); fx4 v = xv[k];
    acc += a.x * v.x + a.y * v.y + a.z * v.z + a.w * v.w;
  }
  if (*ntc) {  // h_tc has nonzeros: add the W_ht stream
    const fx4* __restrict__ Br = (const fx4*)(Wht + (size_t)row * PHASE);
    const fx4* __restrict__ hv = (const fx4*)htc;
    #pragma unroll 4
    for (int k = lane; k < PHASE / 4; k += 64) {
      fx4 bb = ntload4(Br + k); fx4 u = hv[k];
      acc += bb.x * u.x + bb.y * u.y + bb.z * u.z + bb.w * u.w;
    }
  }
  acc = waveReduce(acc);
  if (lane == 0) {
    float hn = tanhf(acc);
    float sg = 1.0f / (1.0f + expf(-gnrt[row]));
    float v = zflat[row] + 0.1f * sg * hn;
    zfb[row] = v;
    red[wave] = v * v;
  }
  __syncthreads();
  if (threadIdx.x == 0) atomicAdd(accums + 1, red[0] + red[1] + red[2] + red[3]);
}

// ---------------------------------------------------------------------------
// Kernel 5: elementwise final where/rescale (norms already in accums).
// ---------------------------------------------------------------------------
__global__ __launch_bounds__(256) void k_out(const float* __restrict__ zfb,
                                             const float* __restrict__ accums,
                                             float* __restrict__ out) {
  int i = blockIdx.x * 256 + threadIdx.x;
  float tn = sqrtf(accums[0]);
  float cn = sqrtf(accums[1]);
  float v = zfb[i];
  float r = v * (tn / fmaxf(cn, NORM_EPS));
  float o = (cn > NORM_EPS) ? r : v;
  o = (tn > NORM_EPS) ? o : 0.0f;
  out[i] = o;
}

extern "C" void kernel_launch(void* const* d_in, const int* in_sizes, int n_in,
                              void* d_out, int out_size, void* d_ws, size_t ws_size,
                              hipStream_t stream) {
  const float* sdr  = (const float*)d_in[0];
  const float* vel  = (const float*)d_in[1];
  const float* W1   = (const float*)d_in[2];
  const float* b1   = (const float*)d_in[3];
  const float* W2   = (const float*)d_in[4];
  const float* b2   = (const float*)d_in[5];
  const float* velW = (const float*)d_in[6];
  const float* Wtc  = (const float*)d_in[7];
  const float* Wht  = (const float*)d_in[8];
  const float* gnrt = (const float*)d_in[9];
  const float* htc  = (const float*)d_in[10];
  float* out = (float*)d_out;

  char* ws = (char*)d_ws;
  unsigned int* masks  = (unsigned int*)ws;                   // 16 KB
  int*          ngrp   = (int*)(ws + 16384);
  int*          ntc    = (int*)(ws + 16384 + 64);
  float*        accums = (float*)(ws + 16384 + 128);          // 2 floats
  unsigned int* packed = (unsigned int*)(ws + 16384 + 256);   // 16 KB
  float* h     = (float*)(ws + 32768 + 512);
  float* zflat = h + HIDDEN;
  float* zfb   = zflat + PHASE;

  k_masks<<<NGRP / 256, 256, 0, stream>>>(sdr, masks, accums);
  k_emit<<<1, 1024, 0, stream>>>(masks, htc, packed, ngrp, ntc);
  k_h<<<HIDDEN / 4, 256, 0, stream>>>(W1, b1, packed, ngrp, h);
  k_z_rot<<<PHASE / 4, 256, 0, stream>>>(W2, h, b2, velW, vel, zflat, accums);
  k_hnew<<<PHASE / 4, 256, 0, stream>>>(Wtc, Wht, zflat, htc, gnrt, ntc, zfb, accums);
  k_out<<<PHASE / 256, 256, 0, stream>>>(zfb, accums, out);
}

// Round 8
// 177.007 us; speedup vs baseline: 1.0930x; 1.0930x over previous
//
#include <hip/hip_runtime.h>
#include <math.h>

#define SDR_DIM 65536
#define HIDDEN  4096
#define NMOD    2048
#define PHASE   4096
#define NGRP    (SDR_DIM / 16)    // 4096 groups of 16 floats (64B lines)
#define NORM_EPS 1e-8f

typedef float fx4 __attribute__((ext_vector_type(4)));

__device__ __forceinline__ float waveReduce(float v) {
  #pragma unroll
  for (int off = 32; off > 0; off >>= 1) v += __shfl_down(v, off);
  return v;
}

__device__ __forceinline__ fx4 ntload4(const fx4* p) {
  return __builtin_nontemporal_load(p);
}

// ---------------------------------------------------------------------------
// Kernel 1a: per-group 16-bit activity masks (parallel over 16 blocks).
// group g = columns [16g, 16g+16) = one 64B line of each W1 row.
// ---------------------------------------------------------------------------
__global__ __launch_bounds__(256) void k_masks(const float* __restrict__ sdr,
                                               unsigned int* __restrict__ masks) {
  int g = blockIdx.x * 256 + threadIdx.x;   // 0..NGRP-1
  const fx4* s4 = (const fx4*)sdr;
  unsigned int m = 0;
  #pragma unroll
  for (int q = 0; q < 4; ++q) {
    fx4 v = s4[g * 4 + q];
    m |= (v.x > 0.0f ? 1u : 0u) << (q * 4 + 0);
    m |= (v.y > 0.0f ? 1u : 0u) << (q * 4 + 1);
    m |= (v.z > 0.0f ? 1u : 0u) << (q * 4 + 2);
    m |= (v.w > 0.0f ? 1u : 0u) << (q * 4 + 3);
  }
  masks[g] = m;
}

// ---------------------------------------------------------------------------
// Kernel 1b: single-block scan over the (L2-hot, 16KB) mask array -> packed
// list (ascending g, deterministic). Also: ntc flag = any(h_tc != 0).
// ---------------------------------------------------------------------------
__global__ __launch_bounds__(1024) void k_emit(const unsigned int* __restrict__ masks,
                                               const float* __restrict__ htc,
                                               unsigned int* __restrict__ packed,
                                               int* __restrict__ ngrp,
                                               int* __restrict__ ntc) {
  __shared__ int wsum[16];
  __shared__ int sflag;
  int t = threadIdx.x;
  int lane = t & 63, wave = t >> 6;
  if (t == 0) sflag = 0;
  __syncthreads();

  bool nz = false;
  #pragma unroll
  for (int i = 0; i < PHASE / 1024; ++i) nz |= (htc[t + i * 1024] != 0.0f);
  if (nz) sflag = 1;

  unsigned int m[4];
  int cnt = 0;
  #pragma unroll
  for (int g = 0; g < 4; ++g) {
    m[g] = masks[t * 4 + g];
    cnt += (m[g] != 0u) ? 1 : 0;
  }
  int inc = cnt;
  #pragma unroll
  for (int d = 1; d < 64; d <<= 1) {
    int v = __shfl_up(inc, d);
    if (lane >= d) inc += v;
  }
  if (lane == 63) wsum[wave] = inc;
  __syncthreads();
  if (t == 0) {
    int s = 0;
    #pragma unroll
    for (int w = 0; w < 16; ++w) { int v = wsum[w]; wsum[w] = s; s += v; }
    *ngrp = s;
    *ntc = sflag;
  }
  __syncthreads();
  int off = wsum[wave] + (inc - cnt);
  #pragma unroll
  for (int g = 0; g < 4; ++g) {
    if (m[g]) packed[off++] = (m[g] << 16) | (unsigned int)(t * 4 + g);
  }
}

// ---------------------------------------------------------------------------
// Kernel 2: h = relu(W1 @ sdr + b1), sparse 64B-line streaming.
// 1 row/wave, 4 waves/block. Lane cluster of 4 covers one line; 8 lines in
// flight per lane. Weight loads non-temporal (zero reuse).
// At the 128B-granularity HBM roofline: ~865MB at ~6.2 TB/s.
// ---------------------------------------------------------------------------
__global__ __launch_bounds__(256) void k_h(const float* __restrict__ W1,
                                           const float* __restrict__ b1,
                                           const unsigned int* __restrict__ packed,
                                           const int* __restrict__ ngrpp,
                                           float* __restrict__ h) {
  int lane = threadIdx.x & 63;
  int row = blockIdx.x * 4 + (threadIdx.x >> 6);
  int n = *ngrpp;
  int sub = lane & 3, slot = lane >> 2;
  int shift = 16 + sub * 4;
  const fx4* __restrict__ Wr4 = (const fx4*)(W1 + (size_t)row * SDR_DIM);

  float acc = 0.0f;
  int k = slot;
  for (; k + 112 < n; k += 128) {
    unsigned int e[8];
    fx4 f[8];
    #pragma unroll
    for (int j = 0; j < 8; ++j) e[j] = packed[k + 16 * j];
    #pragma unroll
    for (int j = 0; j < 8; ++j) f[j] = ntload4(Wr4 + ((e[j] & 0xFFFFu) * 4 + sub));
    #pragma unroll
    for (int j = 0; j < 8; ++j) {
      unsigned int mj = (e[j] >> shift) & 0xFu;
      acc += (mj & 1u) ? f[j].x : 0.0f;
      acc += (mj & 2u) ? f[j].y : 0.0f;
      acc += (mj & 4u) ? f[j].z : 0.0f;
      acc += (mj & 8u) ? f[j].w : 0.0f;
    }
  }
  for (; k < n; k += 16) {
    unsigned int e = packed[k];
    fx4 f = ntload4(Wr4 + ((e & 0xFFFFu) * 4 + sub));
    unsigned int mj = (e >> shift) & 0xFu;
    acc += (mj & 1u) ? f.x : 0.0f;
    acc += (mj & 2u) ? f.y : 0.0f;
    acc += (mj & 4u) ? f.z : 0.0f;
    acc += (mj & 8u) ? f.w : 0.0f;
  }

  acc = waveReduce(acc);
  if (lane == 0) {
    float v = acc + b1[row];
    h[row] = v > 0.0f ? v : 0.0f;
  }
}

// ---------------------------------------------------------------------------
// Kernel 3: z_ego = W2 @ h + b2 (1 row/wave) fused with per-pair rotation.
// No atomics — norms are computed by the single-block finale (cheaper than
// 1024-way same-address atomics; R6/R7 A/B showed atomics cost ~16 us).
// ---------------------------------------------------------------------------
__global__ __launch_bounds__(256) void k_z_rot(const float* __restrict__ W,
                                               const float* __restrict__ x,
                                               const float* __restrict__ b,
                                               const float* __restrict__ velW,
                                               const float* __restrict__ vel,
                                               float* __restrict__ zego,
                                               float* __restrict__ zflat) {
  __shared__ float zs[4];
  int lane = threadIdx.x & 63;
  int wave = threadIdx.x >> 6;
  int row = blockIdx.x * 4 + wave;
  const fx4* __restrict__ Wr = (const fx4*)(W + (size_t)row * HIDDEN);
  const fx4* __restrict__ xv = (const fx4*)x;
  float acc = 0.0f;
  #pragma unroll 4
  for (int k = lane; k < HIDDEN / 4; k += 64) {
    fx4 w = ntload4(Wr + k); fx4 v = xv[k];
    acc += w.x * v.x + w.y * v.y + w.z * v.z + w.w * v.w;
  }
  acc = waveReduce(acc);
  if (lane == 0) {
    float v = acc + b[row];
    zego[row] = v;
    zs[wave] = v;
  }
  __syncthreads();
  if (threadIdx.x < 2) {
    int m = blockIdx.x * 2 + threadIdx.x;      // pair index
    float xx = zs[2 * threadIdx.x];
    float yy = zs[2 * threadIdx.x + 1];
    float th = velW[2 * m] * vel[0] + velW[2 * m + 1] * vel[1];
    float s, c;
    sincosf(th, &s, &c);
    zflat[2 * m]     = c * xx - s * yy;
    zflat[2 * m + 1] = s * xx + c * yy;
  }
}

// ---------------------------------------------------------------------------
// Kernel 4: h_new = tanh(W_tc@z_flat + [W_ht@h_tc if h_tc != 0]);
//           z_fb = z_flat + 0.1*sigmoid(g_nrt)*h_new.  1 row/wave.
// ---------------------------------------------------------------------------
__global__ __launch_bounds__(256) void k_hnew(const float* __restrict__ Wtc,
                                              const float* __restrict__ Wht,
                                              const float* __restrict__ zflat,
                                              const float* __restrict__ htc,
                                              const float* __restrict__ gnrt,
                                              const int* __restrict__ ntc,
                                              float* __restrict__ zfb) {
  int lane = threadIdx.x & 63;
  int row = blockIdx.x * 4 + (threadIdx.x >> 6);
  const fx4* __restrict__ Ar = (const fx4*)(Wtc + (size_t)row * PHASE);
  const fx4* __restrict__ xv = (const fx4*)zflat;
  float acc = 0.0f;
  #pragma unroll 4
  for (int k = lane; k < PHASE / 4; k += 64) {
    fx4 a = ntload4(Ar + k); fx4 v = xv[k];
    acc += a.x * v.x + a.y * v.y + a.z * v.z + a.w * v.w;
  }
  if (*ntc) {  // h_tc has nonzeros: add the W_ht stream
    const fx4* __restrict__ Br = (const fx4*)(Wht + (size_t)row * PHASE);
    const fx4* __restrict__ hv = (const fx4*)htc;
    #pragma unroll 4
    for (int k = lane; k < PHASE / 4; k += 64) {
      fx4 bb = ntload4(Br + k); fx4 u = hv[k];
      acc += bb.x * u.x + bb.y * u.y + bb.z * u.z + bb.w * u.w;
    }
  }
  acc = waveReduce(acc);
  if (lane == 0) {
    float hn = tanhf(acc);
    float sg = 1.0f / (1.0f + expf(-gnrt[row]));
    zfb[row] = zflat[row] + 0.1f * sg * hn;
  }
}

// ---------------------------------------------------------------------------
// Kernel 5: single-block deterministic norms + final where/rescale.
// zego/zfb are 16KB each, L2-hot from the producing kernels.
// ---------------------------------------------------------------------------
__global__ __launch_bounds__(1024) void k_out(const float* __restrict__ zego,
                                              const float* __restrict__ zfb,
                                              float* __restrict__ out) {
  __shared__ float s0[16], s1[16];
  int t = threadIdx.x;
  int lane = t & 63, wave = t >> 6;
  float a = 0.0f, bsum = 0.0f;
  #pragma unroll
  for (int i = 0; i < PHASE / 1024; ++i) {
    float xe = zego[t + i * 1024]; a += xe * xe;
    float xf = zfb[t + i * 1024];  bsum += xf * xf;
  }
  a = waveReduce(a);
  bsum = waveReduce(bsum);
  if (lane == 0) { s0[wave] = a; s1[wave] = bsum; }
  __syncthreads();
  if (t == 0) {
    float ta = 0.0f, tb = 0.0f;
    #pragma unroll
    for (int w = 0; w < 16; ++w) { ta += s0[w]; tb += s1[w]; }
    s0[0] = ta; s1[0] = tb;
  }
  __syncthreads();
  float tn = sqrtf(s0[0]);
  float cn = sqrtf(s1[0]);
  float scale = tn / fmaxf(cn, NORM_EPS);
  #pragma unroll
  for (int i = 0; i < PHASE / 1024; ++i) {
    float v = zfb[t + i * 1024];
    float r = v * scale;
    float o = (cn > NORM_EPS) ? r : v;
    o = (tn > NORM_EPS) ? o : 0.0f;
    out[t + i * 1024] = o;
  }
}

extern "C" void kernel_launch(void* const* d_in, const int* in_sizes, int n_in,
                              void* d_out, int out_size, void* d_ws, size_t ws_size,
                              hipStream_t stream) {
  const float* sdr  = (const float*)d_in[0];
  const float* vel  = (const float*)d_in[1];
  const float* W1   = (const float*)d_in[2];
  const float* b1   = (const float*)d_in[3];
  const float* W2   = (const float*)d_in[4];
  const float* b2   = (const float*)d_in[5];
  const float* velW = (const float*)d_in[6];
  const float* Wtc  = (const float*)d_in[7];
  const float* Wht  = (const float*)d_in[8];
  const float* gnrt = (const float*)d_in[9];
  const float* htc  = (const float*)d_in[10];
  float* out = (float*)d_out;

  char* ws = (char*)d_ws;
  unsigned int* masks  = (unsigned int*)ws;               // 16 KB
  int*          ngrp   = (int*)(ws + 16384);
  int*          ntc    = (int*)(ws + 16384 + 64);
  unsigned int* packed = (unsigned int*)(ws + 16384 + 128);   // 16 KB
  float* h     = (float*)(ws + 32768 + 256);
  float* zego  = h + HIDDEN;
  float* zflat = zego + PHASE;
  float* zfb   = zflat + PHASE;

  k_masks<<<NGRP / 256, 256, 0, stream>>>(sdr, masks);
  k_emit<<<1, 1024, 0, stream>>>(masks, htc, packed, ngrp, ntc);
  k_h<<<HIDDEN / 4, 256, 0, stream>>>(W1, b1, packed, ngrp, h);
  k_z_rot<<<PHASE / 4, 256, 0, stream>>>(W2, h, b2, velW, vel, zego, zflat);
  k_hnew<<<PHASE / 4, 256, 0, stream>>>(Wtc, Wht, zflat, htc, gnrt, ntc, zfb);
  k_out<<<1, 1024, 0, stream>>>(zego, zfb, out);
}